// Round 2
// baseline (8349.059 us; speedup 1.0000x reference)
//
#include <hip/hip_runtime.h>
#include <cstdint>

#define D_MODELC 256
#define D_STATEC 16
#define D_INNERC 512
#define N_LAYERSC 4
#define BATCHC 64
#define SEQC 900
#define LN_EPSF 1e-5f

// ---------------- embed: x[r,:] = color_embed[grid[r],:] + pos_embed[0, r%900, :]
// grid pointer is pre-offset to the chunk's first row; x is chunk-local.
__global__ void embed_kernel(const int* __restrict__ grid,
                             const float* __restrict__ cemb,
                             const float* __restrict__ pemb,
                             float* __restrict__ x) {
  int row = blockIdx.x;          // chunk-local row
  int c = threadIdx.x;           // 0..255
  int s = row % SEQC;
  int g = grid[row];
  x[(size_t)row * D_MODELC + c] = cemb[g * D_MODELC + c] + pemb[s * D_MODELC + c];
}

// ---------------- generic fp32 GEMM: C = A(MxK) * W(KxN) + bias, row-major
// 64x64 tile, 256 threads, 4x4 microtile. K % 16 == 0; M, N arbitrary.
__global__ __launch_bounds__(256) void gemm_bias(
    const float* __restrict__ A, const float* __restrict__ W,
    const float* __restrict__ bias, float* __restrict__ C,
    int M, int N, int K) {
  __shared__ float As[16][68];   // [k][m], padded
  __shared__ float Bs[16][64];   // [k][n]
  int tid = threadIdx.x;
  int tx = tid & 15, ty = tid >> 4;
  int bm = blockIdx.x * 64;
  int bn = blockIdx.y * 64;
  float acc[4][4] = {};
  for (int k0 = 0; k0 < K; k0 += 16) {
    { // load A tile 64x16, transposed into As (row-clamped: extra rows unused)
      int r = tid >> 2;
      int ar = bm + r; if (ar > M - 1) ar = M - 1;
      int c0 = (tid & 3) * 4;
      const float4 av = *(const float4*)(&A[(size_t)ar * K + k0 + c0]);
      As[c0 + 0][r] = av.x; As[c0 + 1][r] = av.y;
      As[c0 + 2][r] = av.z; As[c0 + 3][r] = av.w;
    }
    #pragma unroll
    for (int i = 0; i < 4; ++i) { // load B tile 16x64
      int idx = tid + i * 256;
      int r = idx >> 6, c = idx & 63;
      int col = bn + c;
      Bs[r][c] = (col < N) ? W[(size_t)(k0 + r) * N + col] : 0.f;
    }
    __syncthreads();
    #pragma unroll
    for (int kk = 0; kk < 16; ++kk) {
      float4 a = *(const float4*)(&As[kk][ty * 4]);
      float4 b = *(const float4*)(&Bs[kk][tx * 4]);
      float av[4] = {a.x, a.y, a.z, a.w};
      float bv[4] = {b.x, b.y, b.z, b.w};
      #pragma unroll
      for (int i = 0; i < 4; ++i)
        #pragma unroll
        for (int j = 0; j < 4; ++j)
          acc[i][j] = fmaf(av[i], bv[j], acc[i][j]);
    }
    __syncthreads();
  }
  #pragma unroll
  for (int i = 0; i < 4; ++i) {
    int row = bm + ty * 4 + i;
    #pragma unroll
    for (int j = 0; j < 4; ++j) {
      int col = bn + tx * 4 + j;
      if (row < M && col < N) C[(size_t)row * N + col] = acc[i][j] + bias[col];
    }
  }
}

// ---------------- depthwise causal conv (k=4) + SiLU. xs = xr[...,:512]
__global__ void conv_silu(const float* __restrict__ xr,
                          const float* __restrict__ cw,  // (512,4), layer offset applied
                          const float* __restrict__ cb,  // (512)
                          float* __restrict__ xc, int total) {
  int idx = blockIdx.x * 256 + threadIdx.x;   // < R*512
  if (idx >= total) return;
  int d = idx & 511;
  int bt = idx >> 9;         // chunk-local b*900 + t
  int t = bt % SEQC;
  float4 w = *(const float4*)(&cw[d * 4]);
  float wv[4] = {w.x, w.y, w.z, w.w};
  float acc = cb[d];
  const float* base = xr + (size_t)(bt - t) * 1024 + d;  // row (b,0), channel d
  #pragma unroll
  for (int j = 0; j < 4; ++j) {
    int ts = t - 3 + j;
    if (ts >= 0) acc = fmaf(wv[j], base[(size_t)ts * 1024], acc);
  }
  float s = acc / (1.f + __expf(-acc));   // silu
  xc[(size_t)bt * 512 + d] = s;
}

// ---------------- selective scan + gating, in-place on xc.
// one thread per (b,d); delta/B staged per-128-timestep chunk in LDS.
__global__ __launch_bounds__(64) void scan_gate(
    const float* __restrict__ ssm,   // (R, 32) raw (pre-softplus)
    const float* __restrict__ xr,    // res at [row*1024 + 512 + d]
    const float* __restrict__ A_log, // (512,16) layer offset applied
    const float* __restrict__ Dp,    // (512)
    float* __restrict__ xc) {        // in/out (R,512)
  __shared__ float sb[128 * 32];
  int b = blockIdx.x >> 3;           // chunk-local batch index
  int d = (blockIdx.x & 7) * 64 + threadIdx.x;
  float a[16];
  #pragma unroll
  for (int n = 0; n < 16; ++n) a[n] = -__expf(A_log[d * 16 + n]);
  float Dv = Dp[d];
  float h[16] = {};
  const size_t rowbase = (size_t)b * SEQC;
  for (int t0 = 0; t0 < SEQC; t0 += 128) {
    int len = min(128, SEQC - t0);
    __syncthreads();
    for (int i = threadIdx.x; i < len * 32; i += 64) {
      int tt = i >> 5, n = i & 31;
      float v = ssm[(rowbase + t0 + tt) * 32 + n];
      if (n < 16) v = (v > 20.f) ? v : log1pf(__expf(v));  // softplus(delta)
      sb[i] = v;
    }
    __syncthreads();
    for (int tt = 0; tt < len; ++tt) {
      size_t row = rowbase + t0 + tt;
      float xv = xc[row * 512 + d];
      const float* del = &sb[tt * 32];
      float y = Dv * xv;
      #pragma unroll
      for (int n = 0; n < 16; ++n) {
        float e = __expf(a[n] * del[n]);
        h[n] = fmaf(h[n], e, xv * del[16 + n]);
        y = fmaf(h[n], del[16 + n], y);
      }
      float r = xr[row * 1024 + 512 + d];
      float g = r / (1.f + __expf(-r));   // silu(res)
      xc[row * 512 + d] = y * g;
    }
  }
}

// ---------------- x = LayerNorm(x + o) ; one wave per 256-elem row
__global__ __launch_bounds__(64) void add_ln(
    float* __restrict__ x, const float* __restrict__ o,
    const float* __restrict__ g, const float* __restrict__ bb) {
  size_t base = (size_t)blockIdx.x * 256;
  int lane = threadIdx.x;
  float4 xv = *(const float4*)(&x[base + lane * 4]);
  float4 ov = *(const float4*)(&o[base + lane * 4]);
  float v[4] = {xv.x + ov.x, xv.y + ov.y, xv.z + ov.z, xv.w + ov.w};
  float s = v[0] + v[1] + v[2] + v[3];
  #pragma unroll
  for (int off = 32; off > 0; off >>= 1) s += __shfl_down(s, off);
  float mu = __shfl(s, 0) * (1.f / 256.f);
  float var = 0.f;
  #pragma unroll
  for (int i = 0; i < 4; ++i) { float dd = v[i] - mu; var = fmaf(dd, dd, var); }
  #pragma unroll
  for (int off = 32; off > 0; off >>= 1) var += __shfl_down(var, off);
  float r = rsqrtf(__shfl(var, 0) * (1.f / 256.f) + LN_EPSF);
  float4 gv = *(const float4*)(&g[lane * 4]);
  float4 bv = *(const float4*)(&bb[lane * 4]);
  float4 outv;
  outv.x = (v[0] - mu) * r * gv.x + bv.x;
  outv.y = (v[1] - mu) * r * gv.y + bv.y;
  outv.z = (v[2] - mu) * r * gv.z + bv.z;
  outv.w = (v[3] - mu) * r * gv.w + bv.w;
  *(float4*)(&x[base + lane * 4]) = outv;
}

// ---------------- copy final-token features of this chunk into fin[64][256]
__global__ void extract_final(const float* __restrict__ x, float* __restrict__ fin,
                              int b0) {
  int bb = blockIdx.x;   // chunk-local batch index
  int c = threadIdx.x;   // 0..255
  fin[(size_t)(b0 + bb) * 256 + c] =
      x[((size_t)bb * SEQC + (SEQC - 1)) * D_MODELC + c];
}

// ---------------- final heads on fin[64][256]
__global__ __launch_bounds__(128) void heads_kernel(
    const float* __restrict__ fin,
    const float* __restrict__ cnt1_w, const float* __restrict__ cnt1_b,
    const float* __restrict__ cnt2_w, const float* __restrict__ cnt2_b,
    const float* __restrict__ col1_w, const float* __restrict__ col1_b,
    const float* __restrict__ col2_w, const float* __restrict__ col2_b,
    float* __restrict__ out) {
  int b = blockIdx.x;
  int tid = threadIdx.x;  // 0..127
  __shared__ float f[256];
  __shared__ float hc[128];
  __shared__ float hl[128];
  f[tid] = fin[b * 256 + tid];
  f[tid + 128] = fin[b * 256 + tid + 128];
  __syncthreads();
  float s1 = cnt1_b[tid], s2 = col1_b[tid];
  for (int c = 0; c < 256; ++c) {
    float v = f[c];
    s1 = fmaf(v, cnt1_w[c * 128 + tid], s1);
    s2 = fmaf(v, col1_w[c * 128 + tid], s2);
  }
  hc[tid] = fmaxf(s1, 0.f);
  hl[tid] = fmaxf(s2, 0.f);
  __syncthreads();
  if (tid == 0) {
    float t = cnt2_b[0];
    for (int j = 0; j < 128; ++j) t = fmaf(hc[j], cnt2_w[j], t);
    out[b] = fmaxf(t, 0.f);
  }
  if (tid < 10) {
    float t = col2_b[tid];
    for (int j = 0; j < 128; ++j) t = fmaf(hl[j], col2_w[j * 10 + tid], t);
    out[64 + b * 10 + tid] = fmaxf(t, 0.f);
  }
}

extern "C" void kernel_launch(void* const* d_in, const int* in_sizes, int n_in,
                              void* d_out, int out_size, void* d_ws, size_t ws_size,
                              hipStream_t stream) {
  const int*   grid   = (const int*)d_in[0];
  const float* cemb   = (const float*)d_in[1];
  const float* pemb   = (const float*)d_in[2];
  const float* in_w   = (const float*)d_in[3];
  const float* in_b   = (const float*)d_in[4];
  const float* conv_w = (const float*)d_in[5];
  const float* conv_b = (const float*)d_in[6];
  const float* xproj_w= (const float*)d_in[7];
  const float* xproj_b= (const float*)d_in[8];
  const float* A_log  = (const float*)d_in[9];
  const float* Dp     = (const float*)d_in[10];
  const float* out_w  = (const float*)d_in[11];
  const float* out_b  = (const float*)d_in[12];
  const float* ln_g   = (const float*)d_in[13];
  const float* ln_b   = (const float*)d_in[14];
  const float* cnt1_w = (const float*)d_in[15];
  const float* cnt1_b = (const float*)d_in[16];
  const float* cnt2_w = (const float*)d_in[17];
  const float* cnt2_b = (const float*)d_in[18];
  const float* col1_w = (const float*)d_in[19];
  const float* col1_b = (const float*)d_in[20];
  const float* col2_w = (const float*)d_in[21];
  const float* col2_b = (const float*)d_in[22];

  // per-sequence workspace: (256 + 1024 + 512 + 32 + 256) floats * 900 rows
  const size_t per_seq_bytes = (size_t)SEQC * 2080 * sizeof(float);
  const size_t fin_bytes = (size_t)BATCHC * 256 * sizeof(float);
  int Bc = (int)((ws_size - fin_bytes) / per_seq_bytes);
  if (Bc > BATCHC) Bc = BATCHC;
  if (Bc < 1) Bc = 1;

  float* fin = (float*)d_ws;                 // 64*256 persists for heads
  float* x   = fin + (size_t)BATCHC * 256;   // chunk buffers below
  // laid out for the MAX chunk size actually used (Bc), constant across calls
  size_t Rm = (size_t)Bc * SEQC;
  float* xr  = x   + Rm * 256;
  float* xc  = xr  + Rm * 1024;
  float* ssm = xc  + Rm * 512;
  float* ob  = ssm + Rm * 32;

  for (int b0 = 0; b0 < BATCHC; b0 += Bc) {
    int nb = (BATCHC - b0 < Bc) ? (BATCHC - b0) : Bc;
    int R = nb * SEQC;

    embed_kernel<<<R, 256, 0, stream>>>(grid + (size_t)b0 * SEQC, cemb, pemb, x);

    for (int l = 0; l < N_LAYERSC; ++l) {
      gemm_bias<<<dim3((R + 63) / 64, 1024 / 64), 256, 0, stream>>>(
          x, in_w + (size_t)l * 256 * 1024, in_b + l * 1024, xr, R, 1024, 256);
      conv_silu<<<(R * 512 + 255) / 256, 256, 0, stream>>>(
          xr, conv_w + (size_t)l * 512 * 4, conv_b + l * 512, xc, R * 512);
      gemm_bias<<<dim3((R + 63) / 64, 1), 256, 0, stream>>>(
          xc, xproj_w + (size_t)l * 512 * 32, xproj_b + l * 32, ssm, R, 32, 512);
      scan_gate<<<nb * 8, 64, 0, stream>>>(
          ssm, xr, A_log + (size_t)l * 512 * 16, Dp + l * 512, xc);
      gemm_bias<<<dim3((R + 63) / 64, 256 / 64), 256, 0, stream>>>(
          xc, out_w + (size_t)l * 512 * 256, out_b + l * 256, ob, R, 256, 512);
      add_ln<<<R, 64, 0, stream>>>(x, ob, ln_g, ln_b);
    }

    extract_final<<<nb, 256, 0, stream>>>(x, fin, b0);
  }

  heads_kernel<<<BATCHC, 128, 0, stream>>>(
      fin, cnt1_w, cnt1_b, cnt2_w, cnt2_b, col1_w, col1_b, col2_w, col2_b,
      (float*)d_out);
}

// Round 3
// 6318.028 us; speedup vs baseline: 1.3215x; 1.3215x over previous
//
#include <hip/hip_runtime.h>
#include <cstdint>

#define D_MODELC 256
#define D_STATEC 16
#define D_INNERC 512
#define N_LAYERSC 4
#define BATCHC 64
#define SEQC 900
#define LN_EPSF 1e-5f

typedef __bf16 bf16x8 __attribute__((ext_vector_type(8)));
typedef float floatx4 __attribute__((ext_vector_type(4)));

// ---------------- embed
__global__ void embed_kernel(const int* __restrict__ grid,
                             const float* __restrict__ cemb,
                             const float* __restrict__ pemb,
                             float* __restrict__ x) {
  int row = blockIdx.x;
  int c = threadIdx.x;
  int s = row % SEQC;
  int g = grid[row];
  x[(size_t)row * D_MODELC + c] = cemb[g * D_MODELC + c] + pemb[s * D_MODELC + c];
}

// ---------------- split-bf16 MFMA GEMM: C = A(MxK)*W(KxN) + bias
// 128x64 tile, 256 threads (4 waves), BK=32. K % 32 == 0.
// A ~= Ah+Al, W ~= Wh+Wl (bf16); C = AhWh + AhWl + AlWh (fp32 acc).
#define LDA 40  // padded row stride (bf16 elems); 80 B, 16B-aligned
__global__ __launch_bounds__(256) void gemm_mfma(
    const float* __restrict__ A, const float* __restrict__ W,
    const float* __restrict__ bias, float* __restrict__ C,
    int M, int N, int K) {
  __shared__ __attribute__((aligned(16))) __bf16 Ahs[128 * LDA];
  __shared__ __attribute__((aligned(16))) __bf16 Als[128 * LDA];
  __shared__ __attribute__((aligned(16))) __bf16 Bhs[64 * LDA];
  __shared__ __attribute__((aligned(16))) __bf16 Bls[64 * LDA];
  int tid = threadIdx.x;
  int bm = blockIdx.x * 128;
  int bn = blockIdx.y * 64;
  int lane = tid & 63;
  int w = tid >> 6;
  int lm = lane & 15;
  int kq = lane >> 4;

  floatx4 acc[2][4];
  floatx4 zero = {0.f, 0.f, 0.f, 0.f};
  #pragma unroll
  for (int i = 0; i < 2; ++i)
    #pragma unroll
    for (int j = 0; j < 4; ++j) acc[i][j] = zero;

  int arow = tid >> 3;        // 0..31
  int acol = (tid & 7) * 4;   // 0..28
  int brow = tid >> 4;        // 0..15 (k)
  int bcol = (tid & 15) * 4;  // 0..60 (n)

  for (int k0 = 0; k0 < K; k0 += 32) {
    __syncthreads();
    // stage A tile 128x32 (fp32 -> bf16 hi/lo)
    #pragma unroll
    for (int p = 0; p < 4; ++p) {
      int r = arow + p * 32;
      int ar = bm + r; if (ar > M - 1) ar = M - 1;
      float4 v = *(const float4*)&A[(size_t)ar * K + k0 + acol];
      float vv[4] = {v.x, v.y, v.z, v.w};
      #pragma unroll
      for (int e = 0; e < 4; ++e) {
        __bf16 hh = (__bf16)vv[e];
        Ahs[r * LDA + acol + e] = hh;
        Als[r * LDA + acol + e] = (__bf16)(vv[e] - (float)hh);
      }
    }
    // stage B tile 32x64 transposed -> [n][k]
    #pragma unroll
    for (int p = 0; p < 2; ++p) {
      int kk = brow + p * 16;
      float4 v;
      if (bn + bcol < N) v = *(const float4*)&W[(size_t)(k0 + kk) * N + bn + bcol];
      else { v.x = 0.f; v.y = 0.f; v.z = 0.f; v.w = 0.f; }
      float vv[4] = {v.x, v.y, v.z, v.w};
      #pragma unroll
      for (int e = 0; e < 4; ++e) {
        __bf16 hh = (__bf16)vv[e];
        Bhs[(bcol + e) * LDA + kk] = hh;
        Bls[(bcol + e) * LDA + kk] = (__bf16)(vv[e] - (float)hh);
      }
    }
    __syncthreads();
    bf16x8 ah[2], al[2], bh[4], bl[4];
    #pragma unroll
    for (int mt = 0; mt < 2; ++mt) {
      int r = w * 32 + mt * 16 + lm;
      ah[mt] = *(const bf16x8*)&Ahs[r * LDA + kq * 8];
      al[mt] = *(const bf16x8*)&Als[r * LDA + kq * 8];
    }
    #pragma unroll
    for (int nt = 0; nt < 4; ++nt) {
      int n = nt * 16 + lm;
      bh[nt] = *(const bf16x8*)&Bhs[n * LDA + kq * 8];
      bl[nt] = *(const bf16x8*)&Bls[n * LDA + kq * 8];
    }
    #pragma unroll
    for (int mt = 0; mt < 2; ++mt)
      #pragma unroll
      for (int nt = 0; nt < 4; ++nt) {
        acc[mt][nt] = __builtin_amdgcn_mfma_f32_16x16x32_bf16(ah[mt], bh[nt], acc[mt][nt], 0, 0, 0);
        acc[mt][nt] = __builtin_amdgcn_mfma_f32_16x16x32_bf16(ah[mt], bl[nt], acc[mt][nt], 0, 0, 0);
        acc[mt][nt] = __builtin_amdgcn_mfma_f32_16x16x32_bf16(al[mt], bh[nt], acc[mt][nt], 0, 0, 0);
      }
  }
  // epilogue: row = bm + w*32 + mt*16 + kq*4 + i, col = bn + nt*16 + lm
  #pragma unroll
  for (int mt = 0; mt < 2; ++mt)
    #pragma unroll
    for (int nt = 0; nt < 4; ++nt) {
      int col = bn + nt * 16 + lm;
      #pragma unroll
      for (int i = 0; i < 4; ++i) {
        int row = bm + w * 32 + mt * 16 + kq * 4 + i;
        if (row < M && col < N)
          C[(size_t)row * N + col] = acc[mt][nt][i] + bias[col];
      }
    }
}

// ---------------- depthwise causal conv (k=4) + SiLU
__global__ void conv_silu(const float* __restrict__ xr,
                          const float* __restrict__ cw,
                          const float* __restrict__ cb,
                          float* __restrict__ xc, int total) {
  int idx = blockIdx.x * 256 + threadIdx.x;
  if (idx >= total) return;
  int d = idx & 511;
  int bt = idx >> 9;
  int t = bt % SEQC;
  float4 wv4 = *(const float4*)(&cw[d * 4]);
  float wv[4] = {wv4.x, wv4.y, wv4.z, wv4.w};
  float acc = cb[d];
  const float* base = xr + (size_t)(bt - t) * 1024 + d;
  #pragma unroll
  for (int j = 0; j < 4; ++j) {
    int ts = t - 3 + j;
    if (ts >= 0) acc = fmaf(wv[j], base[(size_t)ts * 1024], acc);
  }
  float s = acc / (1.f + __expf(-acc));
  xc[(size_t)bt * 512 + d] = s;
}

// ---------------- selective scan + gating, LDS-staged chunks, in-place on xc
#define SCAN_T 96
__global__ __launch_bounds__(64) void scan_gate(
    const float* __restrict__ ssm,   // (R,32) raw
    const float* __restrict__ xr,    // res at [row*1024 + 512 + d]
    const float* __restrict__ A_log, // (512,16)
    const float* __restrict__ Dp,    // (512)
    float* __restrict__ xc) {        // in/out (R,512)
  __shared__ float xs[SCAN_T * 64];  // 24 KB
  __shared__ float rs[SCAN_T * 64];  // 24 KB (silu(res))
  __shared__ float sb[SCAN_T * 32];  // 12 KB (softplus(delta) | B)
  int b = blockIdx.x >> 3;
  int dg = (blockIdx.x & 7) * 64;
  int lane = threadIdx.x;
  int d = dg + lane;
  float a[16];
  #pragma unroll
  for (int n = 0; n < 16; ++n) a[n] = -__expf(A_log[d * 16 + n]);
  float Dv = Dp[d];
  float h[16] = {};
  size_t rowbase = (size_t)b * SEQC;

  for (int t0 = 0; t0 < SEQC; t0 += SCAN_T) {
    int len = (SEQC - t0 < SCAN_T) ? (SEQC - t0) : SCAN_T;
    __syncthreads();
    // stage xc + silu(res)
    for (int i = lane; i < len * 16; i += 64) {
      int tt = i >> 4, j4 = (i & 15) * 4;
      size_t row = rowbase + t0 + tt;
      *(float4*)&xs[tt * 64 + j4] = *(const float4*)&xc[row * 512 + dg + j4];
      float4 r = *(const float4*)&xr[row * 1024 + 512 + dg + j4];
      float4 g;
      g.x = r.x / (1.f + __expf(-r.x));
      g.y = r.y / (1.f + __expf(-r.y));
      g.z = r.z / (1.f + __expf(-r.z));
      g.w = r.w / (1.f + __expf(-r.w));
      *(float4*)&rs[tt * 64 + j4] = g;
    }
    // stage ssm with softplus on delta half
    for (int i = lane; i < len * 8; i += 64) {
      int tt = i >> 3, n4 = (i & 7) * 4;
      float4 v = *(const float4*)&ssm[(rowbase + t0 + tt) * 32 + n4];
      if (n4 < 16) {
        v.x = (v.x > 20.f) ? v.x : log1pf(__expf(v.x));
        v.y = (v.y > 20.f) ? v.y : log1pf(__expf(v.y));
        v.z = (v.z > 20.f) ? v.z : log1pf(__expf(v.z));
        v.w = (v.w > 20.f) ? v.w : log1pf(__expf(v.w));
      }
      *(float4*)&sb[tt * 32 + n4] = v;
    }
    __syncthreads();
    for (int tt = 0; tt < len; ++tt) {
      const float4* dv = (const float4*)&sb[tt * 32];
      float4 d0 = dv[0], d1 = dv[1], d2 = dv[2], d3 = dv[3];
      float4 e0 = dv[4], e1 = dv[5], e2 = dv[6], e3 = dv[7];
      float del[16] = {d0.x, d0.y, d0.z, d0.w, d1.x, d1.y, d1.z, d1.w,
                       d2.x, d2.y, d2.z, d2.w, d3.x, d3.y, d3.z, d3.w};
      float Bv[16]  = {e0.x, e0.y, e0.z, e0.w, e1.x, e1.y, e1.z, e1.w,
                       e2.x, e2.y, e2.z, e2.w, e3.x, e3.y, e3.z, e3.w};
      float xv = xs[tt * 64 + lane];
      float y0 = 0.f, y1 = 0.f, y2 = 0.f, y3 = 0.f;
      #pragma unroll
      for (int n = 0; n < 4; ++n) {
        float e = __expf(a[n] * del[n]);
        h[n] = fmaf(h[n], e, xv * Bv[n]);
        y0 = fmaf(h[n], Bv[n], y0);
      }
      #pragma unroll
      for (int n = 4; n < 8; ++n) {
        float e = __expf(a[n] * del[n]);
        h[n] = fmaf(h[n], e, xv * Bv[n]);
        y1 = fmaf(h[n], Bv[n], y1);
      }
      #pragma unroll
      for (int n = 8; n < 12; ++n) {
        float e = __expf(a[n] * del[n]);
        h[n] = fmaf(h[n], e, xv * Bv[n]);
        y2 = fmaf(h[n], Bv[n], y2);
      }
      #pragma unroll
      for (int n = 12; n < 16; ++n) {
        float e = __expf(a[n] * del[n]);
        h[n] = fmaf(h[n], e, xv * Bv[n]);
        y3 = fmaf(h[n], Bv[n], y3);
      }
      float y = fmaf(Dv, xv, (y0 + y1) + (y2 + y3));
      xs[tt * 64 + lane] = y * rs[tt * 64 + lane];
    }
    __syncthreads();
    // write back
    for (int i = lane; i < len * 16; i += 64) {
      int tt = i >> 4, j4 = (i & 15) * 4;
      *(float4*)&xc[(rowbase + t0 + tt) * 512 + dg + j4] =
          *(const float4*)&xs[tt * 64 + j4];
    }
  }
}

// ---------------- x = LayerNorm(x + o)
__global__ __launch_bounds__(64) void add_ln(
    float* __restrict__ x, const float* __restrict__ o,
    const float* __restrict__ g, const float* __restrict__ bb) {
  size_t base = (size_t)blockIdx.x * 256;
  int lane = threadIdx.x;
  float4 xv = *(const float4*)(&x[base + lane * 4]);
  float4 ov = *(const float4*)(&o[base + lane * 4]);
  float v[4] = {xv.x + ov.x, xv.y + ov.y, xv.z + ov.z, xv.w + ov.w};
  float s = v[0] + v[1] + v[2] + v[3];
  #pragma unroll
  for (int off = 32; off > 0; off >>= 1) s += __shfl_down(s, off);
  float mu = __shfl(s, 0) * (1.f / 256.f);
  float var = 0.f;
  #pragma unroll
  for (int i = 0; i < 4; ++i) { float dd = v[i] - mu; var = fmaf(dd, dd, var); }
  #pragma unroll
  for (int off = 32; off > 0; off >>= 1) var += __shfl_down(var, off);
  float r = rsqrtf(__shfl(var, 0) * (1.f / 256.f) + LN_EPSF);
  float4 gv = *(const float4*)(&g[lane * 4]);
  float4 bv = *(const float4*)(&bb[lane * 4]);
  float4 outv;
  outv.x = (v[0] - mu) * r * gv.x + bv.x;
  outv.y = (v[1] - mu) * r * gv.y + bv.y;
  outv.z = (v[2] - mu) * r * gv.z + bv.z;
  outv.w = (v[3] - mu) * r * gv.w + bv.w;
  *(float4*)(&x[base + lane * 4]) = outv;
}

// ---------------- copy final-token features into fin[64][256]
__global__ void extract_final(const float* __restrict__ x, float* __restrict__ fin,
                              int b0) {
  int bb = blockIdx.x;
  int c = threadIdx.x;
  fin[(size_t)(b0 + bb) * 256 + c] =
      x[((size_t)bb * SEQC + (SEQC - 1)) * D_MODELC + c];
}

// ---------------- final heads
__global__ __launch_bounds__(128) void heads_kernel(
    const float* __restrict__ fin,
    const float* __restrict__ cnt1_w, const float* __restrict__ cnt1_b,
    const float* __restrict__ cnt2_w, const float* __restrict__ cnt2_b,
    const float* __restrict__ col1_w, const float* __restrict__ col1_b,
    const float* __restrict__ col2_w, const float* __restrict__ col2_b,
    float* __restrict__ out) {
  int b = blockIdx.x;
  int tid = threadIdx.x;
  __shared__ float f[256];
  __shared__ float hc[128];
  __shared__ float hl[128];
  f[tid] = fin[b * 256 + tid];
  f[tid + 128] = fin[b * 256 + tid + 128];
  __syncthreads();
  float s1 = cnt1_b[tid], s2 = col1_b[tid];
  for (int c = 0; c < 256; ++c) {
    float v = f[c];
    s1 = fmaf(v, cnt1_w[c * 128 + tid], s1);
    s2 = fmaf(v, col1_w[c * 128 + tid], s2);
  }
  hc[tid] = fmaxf(s1, 0.f);
  hl[tid] = fmaxf(s2, 0.f);
  __syncthreads();
  if (tid == 0) {
    float t = cnt2_b[0];
    for (int j = 0; j < 128; ++j) t = fmaf(hc[j], cnt2_w[j], t);
    out[b] = fmaxf(t, 0.f);
  }
  if (tid < 10) {
    float t = col2_b[tid];
    for (int j = 0; j < 128; ++j) t = fmaf(hl[j], col2_w[j * 10 + tid], t);
    out[64 + b * 10 + tid] = fmaxf(t, 0.f);
  }
}

extern "C" void kernel_launch(void* const* d_in, const int* in_sizes, int n_in,
                              void* d_out, int out_size, void* d_ws, size_t ws_size,
                              hipStream_t stream) {
  const int*   grid   = (const int*)d_in[0];
  const float* cemb   = (const float*)d_in[1];
  const float* pemb   = (const float*)d_in[2];
  const float* in_w   = (const float*)d_in[3];
  const float* in_b   = (const float*)d_in[4];
  const float* conv_w = (const float*)d_in[5];
  const float* conv_b = (const float*)d_in[6];
  const float* xproj_w= (const float*)d_in[7];
  const float* xproj_b= (const float*)d_in[8];
  const float* A_log  = (const float*)d_in[9];
  const float* Dp     = (const float*)d_in[10];
  const float* out_w  = (const float*)d_in[11];
  const float* out_b  = (const float*)d_in[12];
  const float* ln_g   = (const float*)d_in[13];
  const float* ln_b   = (const float*)d_in[14];
  const float* cnt1_w = (const float*)d_in[15];
  const float* cnt1_b = (const float*)d_in[16];
  const float* cnt2_w = (const float*)d_in[17];
  const float* cnt2_b = (const float*)d_in[18];
  const float* col1_w = (const float*)d_in[19];
  const float* col1_b = (const float*)d_in[20];
  const float* col2_w = (const float*)d_in[21];
  const float* col2_b = (const float*)d_in[22];

  const size_t per_seq_bytes = (size_t)SEQC * 2080 * sizeof(float);
  const size_t fin_bytes = (size_t)BATCHC * 256 * sizeof(float);
  int Bc = (int)((ws_size - fin_bytes) / per_seq_bytes);
  if (Bc > BATCHC) Bc = BATCHC;
  if (Bc < 1) Bc = 1;

  float* fin = (float*)d_ws;
  float* x   = fin + (size_t)BATCHC * 256;
  size_t Rm = (size_t)Bc * SEQC;
  float* xr  = x   + Rm * 256;
  float* xc  = xr  + Rm * 1024;
  float* ssm = xc  + Rm * 512;
  float* ob  = ssm + Rm * 32;

  for (int b0 = 0; b0 < BATCHC; b0 += Bc) {
    int nb = (BATCHC - b0 < Bc) ? (BATCHC - b0) : Bc;
    int R = nb * SEQC;

    embed_kernel<<<R, 256, 0, stream>>>(grid + (size_t)b0 * SEQC, cemb, pemb, x);

    for (int l = 0; l < N_LAYERSC; ++l) {
      gemm_mfma<<<dim3((R + 127) / 128, 1024 / 64), 256, 0, stream>>>(
          x, in_w + (size_t)l * 256 * 1024, in_b + l * 1024, xr, R, 1024, 256);
      conv_silu<<<(R * 512 + 255) / 256, 256, 0, stream>>>(
          xr, conv_w + (size_t)l * 512 * 4, conv_b + l * 512, xc, R * 512);
      gemm_mfma<<<dim3((R + 127) / 128, 1), 256, 0, stream>>>(
          xc, xproj_w + (size_t)l * 512 * 32, xproj_b + l * 32, ssm, R, 32, 512);
      scan_gate<<<nb * 8, 64, 0, stream>>>(
          ssm, xr, A_log + (size_t)l * 512 * 16, Dp + l * 512, xc);
      gemm_mfma<<<dim3((R + 127) / 128, 256 / 64), 256, 0, stream>>>(
          xc, out_w + (size_t)l * 512 * 256, out_b + l * 256, ob, R, 256, 512);
      add_ln<<<R, 64, 0, stream>>>(x, ob, ln_g, ln_b);
    }

    extract_final<<<nb, 256, 0, stream>>>(x, fin, b0);
  }

  heads_kernel<<<BATCHC, 128, 0, stream>>>(
      fin, cnt1_w, cnt1_b, cnt2_w, cnt2_b, col1_w, col1_b, col2_w, col2_b,
      (float*)d_out);
}

// Round 4
// 5741.649 us; speedup vs baseline: 1.4541x; 1.1004x over previous
//
#include <hip/hip_runtime.h>
#include <cstdint>

#define D_MODELC 256
#define D_STATEC 16
#define D_INNERC 512
#define N_LAYERSC 4
#define BATCHC 64
#define SEQC 900
#define NCH 10
#define CT 90
#define LN_EPSF 1e-5f

typedef __bf16 bf16x8 __attribute__((ext_vector_type(8)));
typedef __bf16 bf16x4 __attribute__((ext_vector_type(4)));
typedef float floatx4 __attribute__((ext_vector_type(4)));

__device__ inline void split2(float v, __bf16* h, __bf16* l) {
  __bf16 hh = (__bf16)v;
  *h = hh;
  *l = (__bf16)(v - (float)hh);
}

// ---------------- weight transpose + split: W (L,K,N) -> Wh/Wl (L,N,K) bf16
__global__ void wsplit(const float* __restrict__ W, __bf16* __restrict__ Wh,
                       __bf16* __restrict__ Wl, int K, int N, int kshift) {
  int l = blockIdx.y;
  int idx = blockIdx.x * 256 + threadIdx.x;
  if (idx >= N * K) return;
  int n = idx >> kshift, k = idx & (K - 1);
  float v = W[(size_t)l * K * N + (size_t)k * N + n];
  __bf16 hh = (__bf16)v;
  Wh[(size_t)l * N * K + idx] = hh;
  Wl[(size_t)l * N * K + idx] = (__bf16)(v - (float)hh);
}

// ---------------- embed + split
__global__ void embed_kernel(const int* __restrict__ grid,
                             const float* __restrict__ cemb,
                             const float* __restrict__ pemb,
                             float* __restrict__ x,
                             __bf16* __restrict__ xh, __bf16* __restrict__ xl) {
  int row = blockIdx.x;
  int c = threadIdx.x;
  int s = row % SEQC;
  int g = grid[row];
  float v = cemb[g * D_MODELC + c] + pemb[s * D_MODELC + c];
  size_t o = (size_t)row * D_MODELC + c;
  x[o] = v;
  split2(v, &xh[o], &xl[o]);
}

// ---------------- split-bf16 MFMA GEMM: C = A(MxK)*B^T(NxK) + bias
// 128x128 tile, 256 threads (4 waves 2x2), BK=32. A,B pre-split bf16.
#define GLDA 40
__global__ __launch_bounds__(256) void gemm_split(
    const __bf16* __restrict__ Ah, const __bf16* __restrict__ Al,
    const __bf16* __restrict__ Bh, const __bf16* __restrict__ Bl,
    const float* __restrict__ bias, float* __restrict__ C,
    int M, int N, int K) {
  __shared__ __attribute__((aligned(16))) __bf16 Ahs[128 * GLDA];
  __shared__ __attribute__((aligned(16))) __bf16 Als[128 * GLDA];
  __shared__ __attribute__((aligned(16))) __bf16 Bhs[128 * GLDA];
  __shared__ __attribute__((aligned(16))) __bf16 Bls[128 * GLDA];
  int tid = threadIdx.x, lane = tid & 63, w = tid >> 6;
  int bm = blockIdx.x * 128, bn = blockIdx.y * 128;
  int wm = (w >> 1) * 64, wn = (w & 1) * 64;
  int lm = lane & 15, kq = lane >> 4;

  floatx4 acc[4][4];
  floatx4 zero = {0.f, 0.f, 0.f, 0.f};
  #pragma unroll
  for (int i = 0; i < 4; ++i)
    #pragma unroll
    for (int j = 0; j < 4; ++j) acc[i][j] = zero;

  int r0 = tid >> 2;          // 0..63
  int kb = (tid & 3) * 8;     // 0,8,16,24

  for (int k0 = 0; k0 < K; k0 += 32) {
    __syncthreads();
    #pragma unroll
    for (int p = 0; p < 2; ++p) {
      int r = r0 + p * 64;
      int ar = bm + r; if (ar > M - 1) ar = M - 1;
      size_t aoff = (size_t)ar * K + k0 + kb;
      *(bf16x8*)&Ahs[r * GLDA + kb] = *(const bf16x8*)&Ah[aoff];
      *(bf16x8*)&Als[r * GLDA + kb] = *(const bf16x8*)&Al[aoff];
      int nr = bn + r;
      if (nr < N) {
        size_t boff = (size_t)nr * K + k0 + kb;
        *(bf16x8*)&Bhs[r * GLDA + kb] = *(const bf16x8*)&Bh[boff];
        *(bf16x8*)&Bls[r * GLDA + kb] = *(const bf16x8*)&Bl[boff];
      } else {
        uint4 zu = make_uint4(0, 0, 0, 0);
        *(uint4*)&Bhs[r * GLDA + kb] = zu;
        *(uint4*)&Bls[r * GLDA + kb] = zu;
      }
    }
    __syncthreads();
    bf16x8 fah[4], fal[4], fbh[4], fbl[4];
    #pragma unroll
    for (int mt = 0; mt < 4; ++mt) {
      int rr = wm + mt * 16 + lm;
      fah[mt] = *(const bf16x8*)&Ahs[rr * GLDA + kq * 8];
      fal[mt] = *(const bf16x8*)&Als[rr * GLDA + kq * 8];
    }
    #pragma unroll
    for (int nt = 0; nt < 4; ++nt) {
      int nn = wn + nt * 16 + lm;
      fbh[nt] = *(const bf16x8*)&Bhs[nn * GLDA + kq * 8];
      fbl[nt] = *(const bf16x8*)&Bls[nn * GLDA + kq * 8];
    }
    #pragma unroll
    for (int mt = 0; mt < 4; ++mt)
      #pragma unroll
      for (int nt = 0; nt < 4; ++nt) {
        acc[mt][nt] = __builtin_amdgcn_mfma_f32_16x16x32_bf16(fah[mt], fbh[nt], acc[mt][nt], 0, 0, 0);
        acc[mt][nt] = __builtin_amdgcn_mfma_f32_16x16x32_bf16(fah[mt], fbl[nt], acc[mt][nt], 0, 0, 0);
        acc[mt][nt] = __builtin_amdgcn_mfma_f32_16x16x32_bf16(fal[mt], fbh[nt], acc[mt][nt], 0, 0, 0);
      }
  }
  #pragma unroll
  for (int mt = 0; mt < 4; ++mt)
    #pragma unroll
    for (int nt = 0; nt < 4; ++nt) {
      int col = bn + wn + nt * 16 + lm;
      #pragma unroll
      for (int i = 0; i < 4; ++i) {
        int row = bm + wm + mt * 16 + kq * 4 + i;
        if (row < M && col < N)
          C[(size_t)row * N + col] = acc[mt][nt][i] + bias[col];
      }
    }
}

// ---------------- depthwise causal conv (k=4) + SiLU + split
__global__ void conv_silu(const float* __restrict__ xr,
                          const float* __restrict__ cw,
                          const float* __restrict__ cb,
                          float* __restrict__ xc,
                          __bf16* __restrict__ xch, __bf16* __restrict__ xcl,
                          int total) {
  int idx = blockIdx.x * 256 + threadIdx.x;
  if (idx >= total) return;
  int d = idx & 511;
  int bt = idx >> 9;
  int t = bt % SEQC;
  float4 wv4 = *(const float4*)(&cw[d * 4]);
  float wv[4] = {wv4.x, wv4.y, wv4.z, wv4.w};
  float acc = cb[d];
  const float* base = xr + (size_t)(bt - t) * 1024 + d;
  #pragma unroll
  for (int j = 0; j < 4; ++j) {
    int ts = t - 3 + j;
    if (ts >= 0) acc = fmaf(wv[j], base[(size_t)ts * 1024], acc);
  }
  float s = acc / (1.f + __expf(-acc));
  size_t o = (size_t)bt * 512 + d;
  xc[o] = s;
  split2(s, &xch[o], &xcl[o]);
}

// ---------------- scan phase 1: per-chunk local scan (h_in=0) -> h_end, P
__global__ __launch_bounds__(64) void scan_phase1(
    const float* __restrict__ ssm, const float* __restrict__ A_log,
    const float* __restrict__ xc,
    float* __restrict__ hend, float* __restrict__ Pp) {
  __shared__ float sb[CT * 32];
  __shared__ float xs[CT * 64];
  int b = blockIdx.x;
  int dg = blockIdx.y * 64;
  int c = blockIdx.z;
  int lane = threadIdx.x;
  int d = dg + lane;
  float a[16];
  #pragma unroll
  for (int n = 0; n < 16; ++n) a[n] = -__expf(A_log[d * 16 + n]);
  size_t rowbase = (size_t)b * SEQC + c * CT;

  for (int i = lane; i < CT * 8; i += 64) {
    int tt = i >> 3, n4 = (i & 7) * 4;
    float4 v = *(const float4*)&ssm[(rowbase + tt) * 32 + n4];
    if (n4 < 16) {
      v.x = (v.x > 20.f) ? v.x : log1pf(__expf(v.x));
      v.y = (v.y > 20.f) ? v.y : log1pf(__expf(v.y));
      v.z = (v.z > 20.f) ? v.z : log1pf(__expf(v.z));
      v.w = (v.w > 20.f) ? v.w : log1pf(__expf(v.w));
    }
    *(float4*)&sb[tt * 32 + n4] = v;
  }
  for (int i = lane; i < CT * 16; i += 64) {
    int tt = i >> 4, j4 = (i & 15) * 4;
    *(float4*)&xs[tt * 64 + j4] = *(const float4*)&xc[(rowbase + tt) * 512 + dg + j4];
  }
  __syncthreads();
  float h[16] = {};
  float S[16] = {};
  for (int tt = 0; tt < CT; ++tt) {
    const float4* dv = (const float4*)&sb[tt * 32];
    float4 d0 = dv[0], d1 = dv[1], d2 = dv[2], d3 = dv[3];
    float4 e0 = dv[4], e1 = dv[5], e2 = dv[6], e3 = dv[7];
    float del[16] = {d0.x, d0.y, d0.z, d0.w, d1.x, d1.y, d1.z, d1.w,
                     d2.x, d2.y, d2.z, d2.w, d3.x, d3.y, d3.z, d3.w};
    float Bv[16]  = {e0.x, e0.y, e0.z, e0.w, e1.x, e1.y, e1.z, e1.w,
                     e2.x, e2.y, e2.z, e2.w, e3.x, e3.y, e3.z, e3.w};
    float xv = xs[tt * 64 + lane];
    #pragma unroll
    for (int n = 0; n < 16; ++n) {
      S[n] += del[n];
      float e = __expf(a[n] * del[n]);
      h[n] = fmaf(h[n], e, xv * Bv[n]);
    }
  }
  size_t base = ((size_t)(b * NCH + c) * 512 + d) * 16;
  #pragma unroll
  for (int n = 0; n < 16; ++n) {
    hend[base + n] = h[n];
    Pp[base + n] = __expf(a[n] * S[n]);
  }
}

// ---------------- scan phase 2: sequential chunk-carry composition
__global__ __launch_bounds__(64) void scan_combine(
    const float* __restrict__ hend, const float* __restrict__ Pp,
    float* __restrict__ hin) {
  int b = blockIdx.x;
  int d = blockIdx.y * 64 + threadIdx.x;
  float hp[16] = {};
  for (int c = 0; c < NCH; ++c) {
    size_t base = ((size_t)(b * NCH + c) * 512 + d) * 16;
    #pragma unroll
    for (int n = 0; n < 16; ++n) {
      hin[base + n] = hp[n];
      hp[n] = fmaf(Pp[base + n], hp[n], hend[base + n]);
    }
  }
}

// ---------------- scan phase 3: full local scan with carry, y, gate, split
__global__ __launch_bounds__(64) void scan_phase3(
    const float* __restrict__ ssm, const float* __restrict__ A_log,
    const float* __restrict__ Dp, const float* __restrict__ xc,
    const float* __restrict__ xr, const float* __restrict__ hin,
    __bf16* __restrict__ ych, __bf16* __restrict__ ycl) {
  __shared__ float sb[CT * 32];
  __shared__ float xs[CT * 64];
  int b = blockIdx.x;
  int dg = blockIdx.y * 64;
  int c = blockIdx.z;
  int lane = threadIdx.x;
  int d = dg + lane;
  float a[16];
  #pragma unroll
  for (int n = 0; n < 16; ++n) a[n] = -__expf(A_log[d * 16 + n]);
  float Dv = Dp[d];
  size_t rowbase = (size_t)b * SEQC + c * CT;

  for (int i = lane; i < CT * 8; i += 64) {
    int tt = i >> 3, n4 = (i & 7) * 4;
    float4 v = *(const float4*)&ssm[(rowbase + tt) * 32 + n4];
    if (n4 < 16) {
      v.x = (v.x > 20.f) ? v.x : log1pf(__expf(v.x));
      v.y = (v.y > 20.f) ? v.y : log1pf(__expf(v.y));
      v.z = (v.z > 20.f) ? v.z : log1pf(__expf(v.z));
      v.w = (v.w > 20.f) ? v.w : log1pf(__expf(v.w));
    }
    *(float4*)&sb[tt * 32 + n4] = v;
  }
  for (int i = lane; i < CT * 16; i += 64) {
    int tt = i >> 4, j4 = (i & 15) * 4;
    *(float4*)&xs[tt * 64 + j4] = *(const float4*)&xc[(rowbase + tt) * 512 + dg + j4];
  }
  __syncthreads();
  float h[16];
  {
    size_t base = ((size_t)(b * NCH + c) * 512 + d) * 16;
    #pragma unroll
    for (int n = 0; n < 16; ++n) h[n] = hin[base + n];
  }
  for (int tt = 0; tt < CT; ++tt) {
    const float4* dv = (const float4*)&sb[tt * 32];
    float4 d0 = dv[0], d1 = dv[1], d2 = dv[2], d3 = dv[3];
    float4 e0 = dv[4], e1 = dv[5], e2 = dv[6], e3 = dv[7];
    float del[16] = {d0.x, d0.y, d0.z, d0.w, d1.x, d1.y, d1.z, d1.w,
                     d2.x, d2.y, d2.z, d2.w, d3.x, d3.y, d3.z, d3.w};
    float Bv[16]  = {e0.x, e0.y, e0.z, e0.w, e1.x, e1.y, e1.z, e1.w,
                     e2.x, e2.y, e2.z, e2.w, e3.x, e3.y, e3.z, e3.w};
    float xv = xs[tt * 64 + lane];
    float y0 = 0.f, y1 = 0.f, y2 = 0.f, y3 = 0.f;
    #pragma unroll
    for (int n = 0; n < 4; ++n) {
      float e = __expf(a[n] * del[n]);
      h[n] = fmaf(h[n], e, xv * Bv[n]);
      y0 = fmaf(h[n], Bv[n], y0);
    }
    #pragma unroll
    for (int n = 4; n < 8; ++n) {
      float e = __expf(a[n] * del[n]);
      h[n] = fmaf(h[n], e, xv * Bv[n]);
      y1 = fmaf(h[n], Bv[n], y1);
    }
    #pragma unroll
    for (int n = 8; n < 12; ++n) {
      float e = __expf(a[n] * del[n]);
      h[n] = fmaf(h[n], e, xv * Bv[n]);
      y2 = fmaf(h[n], Bv[n], y2);
    }
    #pragma unroll
    for (int n = 12; n < 16; ++n) {
      float e = __expf(a[n] * del[n]);
      h[n] = fmaf(h[n], e, xv * Bv[n]);
      y3 = fmaf(h[n], Bv[n], y3);
    }
    xs[tt * 64 + lane] = fmaf(Dv, xv, (y0 + y1) + (y2 + y3));
  }
  __syncthreads();
  // gate with silu(res) and write split bf16
  for (int i = lane; i < CT * 16; i += 64) {
    int tt = i >> 4, j4 = (i & 15) * 4;
    float4 y4 = *(const float4*)&xs[tt * 64 + j4];
    float4 r4 = *(const float4*)&xr[(rowbase + tt) * 1024 + 512 + dg + j4];
    float yv[4] = {y4.x, y4.y, y4.z, y4.w};
    float rv[4] = {r4.x, r4.y, r4.z, r4.w};
    bf16x4 hq, lq;
    #pragma unroll
    for (int e = 0; e < 4; ++e) {
      float g = rv[e] / (1.f + __expf(-rv[e]));
      float v = yv[e] * g;
      __bf16 hh = (__bf16)v;
      hq[e] = hh;
      lq[e] = (__bf16)(v - (float)hh);
    }
    size_t o = (rowbase + tt) * 512 + dg + j4;
    *(bf16x4*)&ych[o] = hq;
    *(bf16x4*)&ycl[o] = lq;
  }
}

// ---------------- x = LayerNorm(x + o) + split
__global__ __launch_bounds__(64) void add_ln(
    float* __restrict__ x, const float* __restrict__ o,
    const float* __restrict__ g, const float* __restrict__ bb,
    __bf16* __restrict__ xh, __bf16* __restrict__ xl) {
  size_t base = (size_t)blockIdx.x * 256;
  int lane = threadIdx.x;
  float4 xv = *(const float4*)(&x[base + lane * 4]);
  float4 ov = *(const float4*)(&o[base + lane * 4]);
  float v[4] = {xv.x + ov.x, xv.y + ov.y, xv.z + ov.z, xv.w + ov.w};
  float s = v[0] + v[1] + v[2] + v[3];
  #pragma unroll
  for (int off = 32; off > 0; off >>= 1) s += __shfl_down(s, off);
  float mu = __shfl(s, 0) * (1.f / 256.f);
  float var = 0.f;
  #pragma unroll
  for (int i = 0; i < 4; ++i) { float dd = v[i] - mu; var = fmaf(dd, dd, var); }
  #pragma unroll
  for (int off = 32; off > 0; off >>= 1) var += __shfl_down(var, off);
  float r = rsqrtf(__shfl(var, 0) * (1.f / 256.f) + LN_EPSF);
  float4 gv = *(const float4*)(&g[lane * 4]);
  float4 bv = *(const float4*)(&bb[lane * 4]);
  float gg[4] = {gv.x, gv.y, gv.z, gv.w};
  float bbv[4] = {bv.x, bv.y, bv.z, bv.w};
  float outv[4];
  bf16x4 hq, lq;
  #pragma unroll
  for (int i = 0; i < 4; ++i) {
    outv[i] = (v[i] - mu) * r * gg[i] + bbv[i];
    __bf16 hh = (__bf16)outv[i];
    hq[i] = hh;
    lq[i] = (__bf16)(outv[i] - (float)hh);
  }
  float4 ov2 = {outv[0], outv[1], outv[2], outv[3]};
  *(float4*)(&x[base + lane * 4]) = ov2;
  *(bf16x4*)&xh[base + lane * 4] = hq;
  *(bf16x4*)&xl[base + lane * 4] = lq;
}

// ---------------- copy final-token features into fin[64][256]
__global__ void extract_final(const float* __restrict__ x, float* __restrict__ fin,
                              int b0) {
  int bb = blockIdx.x;
  int c = threadIdx.x;
  fin[(size_t)(b0 + bb) * 256 + c] =
      x[((size_t)bb * SEQC + (SEQC - 1)) * D_MODELC + c];
}

// ---------------- final heads
__global__ __launch_bounds__(128) void heads_kernel(
    const float* __restrict__ fin,
    const float* __restrict__ cnt1_w, const float* __restrict__ cnt1_b,
    const float* __restrict__ cnt2_w, const float* __restrict__ cnt2_b,
    const float* __restrict__ col1_w, const float* __restrict__ col1_b,
    const float* __restrict__ col2_w, const float* __restrict__ col2_b,
    float* __restrict__ out) {
  int b = blockIdx.x;
  int tid = threadIdx.x;
  __shared__ float f[256];
  __shared__ float hc[128];
  __shared__ float hl[128];
  f[tid] = fin[b * 256 + tid];
  f[tid + 128] = fin[b * 256 + tid + 128];
  __syncthreads();
  float s1 = cnt1_b[tid], s2 = col1_b[tid];
  for (int c = 0; c < 256; ++c) {
    float v = f[c];
    s1 = fmaf(v, cnt1_w[c * 128 + tid], s1);
    s2 = fmaf(v, col1_w[c * 128 + tid], s2);
  }
  hc[tid] = fmaxf(s1, 0.f);
  hl[tid] = fmaxf(s2, 0.f);
  __syncthreads();
  if (tid == 0) {
    float t = cnt2_b[0];
    for (int j = 0; j < 128; ++j) t = fmaf(hc[j], cnt2_w[j], t);
    out[b] = fmaxf(t, 0.f);
  }
  if (tid < 10) {
    float t = col2_b[tid];
    for (int j = 0; j < 128; ++j) t = fmaf(hl[j], col2_w[j * 10 + tid], t);
    out[64 + b * 10 + tid] = fmaxf(t, 0.f);
  }
}

extern "C" void kernel_launch(void* const* d_in, const int* in_sizes, int n_in,
                              void* d_out, int out_size, void* d_ws, size_t ws_size,
                              hipStream_t stream) {
  const int*   grid   = (const int*)d_in[0];
  const float* cemb   = (const float*)d_in[1];
  const float* pemb   = (const float*)d_in[2];
  const float* in_w   = (const float*)d_in[3];
  const float* in_b   = (const float*)d_in[4];
  const float* conv_w = (const float*)d_in[5];
  const float* conv_b = (const float*)d_in[6];
  const float* xproj_w= (const float*)d_in[7];
  const float* xproj_b= (const float*)d_in[8];
  const float* A_log  = (const float*)d_in[9];
  const float* Dp     = (const float*)d_in[10];
  const float* out_w  = (const float*)d_in[11];
  const float* out_b  = (const float*)d_in[12];
  const float* ln_g   = (const float*)d_in[13];
  const float* ln_b   = (const float*)d_in[14];
  const float* cnt1_w = (const float*)d_in[15];
  const float* cnt1_b = (const float*)d_in[16];
  const float* cnt2_w = (const float*)d_in[17];
  const float* cnt2_b = (const float*)d_in[18];
  const float* col1_w = (const float*)d_in[19];
  const float* col1_b = (const float*)d_in[20];
  const float* col2_w = (const float*)d_in[21];
  const float* col2_b = (const float*)d_in[22];

  float* ws = (float*)d_ws;
  size_t off = 0;
  auto alloc = [&](size_t fl) { float* p = ws + off; off += (fl + 63) & ~(size_t)63; return p; };

  float* fin = alloc((size_t)BATCHC * 256);
  // weight split buffers (bf16 stored in float-sized units: 2 bf16 per float)
  __bf16* wih = (__bf16*)alloc((size_t)N_LAYERSC * 1024 * 256 / 2);
  __bf16* wil = (__bf16*)alloc((size_t)N_LAYERSC * 1024 * 256 / 2);
  __bf16* wxh = (__bf16*)alloc((size_t)N_LAYERSC * 32 * 512 / 2);
  __bf16* wxl = (__bf16*)alloc((size_t)N_LAYERSC * 32 * 512 / 2);
  __bf16* woh = (__bf16*)alloc((size_t)N_LAYERSC * 256 * 512 / 2);
  __bf16* wol = (__bf16*)alloc((size_t)N_LAYERSC * 256 * 512 / 2);

  // adaptive batch-chunking to fit ws_size
  const size_t per_seq_fl = (size_t)3360 * SEQC + 3 * (size_t)NCH * 512 * 16 + 1024;
  size_t avail = ws_size / 4 - off;
  int Bc = (int)(avail / per_seq_fl);
  if (Bc > BATCHC) Bc = BATCHC;
  if (Bc < 1) Bc = 1;
  size_t Rm = (size_t)Bc * SEQC;

  float*  x   = alloc(Rm * 256);
  __bf16* xh  = (__bf16*)alloc(Rm * 128);
  __bf16* xl  = (__bf16*)alloc(Rm * 128);
  float*  xr  = alloc(Rm * 1024);
  float*  xc  = alloc(Rm * 512);
  __bf16* xch = (__bf16*)alloc(Rm * 256);
  __bf16* xcl = (__bf16*)alloc(Rm * 256);
  __bf16* ych = (__bf16*)alloc(Rm * 256);
  __bf16* ycl = (__bf16*)alloc(Rm * 256);
  float*  ssm = alloc(Rm * 32);
  float*  ob  = alloc(Rm * 256);
  float*  hend= alloc((size_t)Bc * NCH * 512 * 16);
  float*  hin = alloc((size_t)Bc * NCH * 512 * 16);
  float*  Pp  = alloc((size_t)Bc * NCH * 512 * 16);

  // --- weight prep (once per call)
  wsplit<<<dim3((256 * 1024 + 255) / 256, N_LAYERSC), 256, 0, stream>>>(
      in_w, wih, wil, 256, 1024, 8);
  wsplit<<<dim3((512 * 32 + 255) / 256, N_LAYERSC), 256, 0, stream>>>(
      xproj_w, wxh, wxl, 512, 32, 9);
  wsplit<<<dim3((512 * 256 + 255) / 256, N_LAYERSC), 256, 0, stream>>>(
      out_w, woh, wol, 512, 256, 9);

  for (int b0 = 0; b0 < BATCHC; b0 += Bc) {
    int nb = (BATCHC - b0 < Bc) ? (BATCHC - b0) : Bc;
    int R = nb * SEQC;

    embed_kernel<<<R, 256, 0, stream>>>(grid + (size_t)b0 * SEQC, cemb, pemb,
                                        x, xh, xl);

    for (int l = 0; l < N_LAYERSC; ++l) {
      gemm_split<<<dim3((R + 127) / 128, 8), 256, 0, stream>>>(
          xh, xl, wih + (size_t)l * 1024 * 256, wil + (size_t)l * 1024 * 256,
          in_b + l * 1024, xr, R, 1024, 256);
      conv_silu<<<(R * 512 + 255) / 256, 256, 0, stream>>>(
          xr, conv_w + (size_t)l * 512 * 4, conv_b + l * 512, xc, xch, xcl,
          R * 512);
      gemm_split<<<dim3((R + 127) / 128, 1), 256, 0, stream>>>(
          xch, xcl, wxh + (size_t)l * 32 * 512, wxl + (size_t)l * 32 * 512,
          xproj_b + l * 32, ssm, R, 32, 512);
      scan_phase1<<<dim3(nb, 8, NCH), 64, 0, stream>>>(
          ssm, A_log + (size_t)l * 512 * 16, xc, hend, Pp);
      scan_combine<<<dim3(nb, 8), 64, 0, stream>>>(hend, Pp, hin);
      scan_phase3<<<dim3(nb, 8, NCH), 64, 0, stream>>>(
          ssm, A_log + (size_t)l * 512 * 16, Dp + l * 512, xc, xr, hin,
          ych, ycl);
      gemm_split<<<dim3((R + 127) / 128, 2), 256, 0, stream>>>(
          ych, ycl, woh + (size_t)l * 256 * 512, wol + (size_t)l * 256 * 512,
          out_b + l * 256, ob, R, 256, 512);
      add_ln<<<R, 64, 0, stream>>>(x, ob, ln_g, ln_b, xh, xl);
    }

    extract_final<<<nb, 256, 0, stream>>>(x, fin, b0);
  }

  heads_kernel<<<BATCHC, 128, 0, stream>>>(
      fin, cnt1_w, cnt1_b, cnt2_w, cnt2_b, col1_w, col1_b, col2_w, col2_b,
      (float*)d_out);
}

// Round 5
// 2689.610 us; speedup vs baseline: 3.1042x; 2.1348x over previous
//
#include <hip/hip_runtime.h>
#include <cstdint>

#define D_MODELC 256
#define N_LAYERSC 4
#define BATCHC 64
#define SEQC 900
#define NCH 10
#define CT 90
#define SUB 45
#define LN_EPSF 1e-5f

typedef __bf16 bf16x8 __attribute__((ext_vector_type(8)));
typedef __bf16 bf16x4 __attribute__((ext_vector_type(4)));
typedef float floatx4 __attribute__((ext_vector_type(4)));

__device__ inline float sp(float v) { return (v > 20.f) ? v : log1pf(__expf(v)); }
__device__ inline float silu(float v) { return v / (1.f + __expf(-v)); }

// ---------------- weight transpose + cvt: W (L,K,N) -> Wb (L,N,K) bf16
__global__ void wprep(const float* __restrict__ W, __bf16* __restrict__ Wb,
                      int K, int N, int kshift) {
  int l = blockIdx.y;
  int idx = blockIdx.x * 256 + threadIdx.x;
  if (idx >= N * K) return;
  int n = idx >> kshift, k = idx & (K - 1);
  Wb[(size_t)l * N * K + idx] = (__bf16)W[(size_t)l * K * N + (size_t)k * N + n];
}

// ---------------- embed -> split bf16 x
__global__ void embed_kernel(const int* __restrict__ grid,
                             const float* __restrict__ cemb,
                             const float* __restrict__ pemb,
                             __bf16* __restrict__ xh, __bf16* __restrict__ xl) {
  int row = blockIdx.x;
  int c = threadIdx.x;
  int s = row % SEQC;
  int g = grid[row];
  float v = cemb[g * D_MODELC + c] + pemb[s * D_MODELC + c];
  size_t o = (size_t)row * D_MODELC + c;
  __bf16 hh = (__bf16)v;
  xh[o] = hh;
  xl[o] = (__bf16)(v - (float)hh);
}

// ---------------- bf16 MFMA GEMM: C = A(MxK) * W^T(NxK) + bias
// 128x128 tile, 4 waves (2x2), BK=32. M % 128 == 0, K % 32 == 0.
// mode 0: fp32 out Cf[row*N+col]
// mode 1: bf16 out Cb[row*N+col]  (col<N guard)
// mode 2: in-proj: col<512 -> Cb[row*512+col]=v ; col>=512 -> Cg[row*512+col-512]=silu(v)
#define GLDA 44
__global__ __launch_bounds__(256) void gemm_bf16(
    const __bf16* __restrict__ A, const __bf16* __restrict__ W,
    const float* __restrict__ bias,
    float* __restrict__ Cf, __bf16* __restrict__ Cb, __bf16* __restrict__ Cg,
    int M, int N, int K, int mode) {
  __shared__ __attribute__((aligned(16))) __bf16 As[128 * GLDA];
  __shared__ __attribute__((aligned(16))) __bf16 Bs[128 * GLDA];
  int tid = threadIdx.x, lane = tid & 63, w = tid >> 6;
  int bm = blockIdx.x * 128, bn = blockIdx.y * 128;
  int wm = (w >> 1) * 64, wn = (w & 1) * 64;
  int lm = lane & 15, kq = lane >> 4;

  floatx4 acc[4][4];
  floatx4 zero = {0.f, 0.f, 0.f, 0.f};
  #pragma unroll
  for (int i = 0; i < 4; ++i)
    #pragma unroll
    for (int j = 0; j < 4; ++j) acc[i][j] = zero;

  int r0 = tid >> 1;          // 0..127
  int kb = (tid & 1) * 16;    // 0 / 16

  for (int k0 = 0; k0 < K; k0 += 32) {
    __syncthreads();
    {
      size_t aoff = (size_t)(bm + r0) * K + k0 + kb;
      *(bf16x8*)&As[r0 * GLDA + kb]     = *(const bf16x8*)&A[aoff];
      *(bf16x8*)&As[r0 * GLDA + kb + 8] = *(const bf16x8*)&A[aoff + 8];
      int nr = bn + r0;
      if (nr < N) {
        size_t boff = (size_t)nr * K + k0 + kb;
        *(bf16x8*)&Bs[r0 * GLDA + kb]     = *(const bf16x8*)&W[boff];
        *(bf16x8*)&Bs[r0 * GLDA + kb + 8] = *(const bf16x8*)&W[boff + 8];
      } else {
        uint4 zu = make_uint4(0, 0, 0, 0);
        *(uint4*)&Bs[r0 * GLDA + kb] = zu;
        *(uint4*)&Bs[r0 * GLDA + kb + 8] = zu;
      }
    }
    __syncthreads();
    bf16x8 fa[4], fb[4];
    #pragma unroll
    for (int mt = 0; mt < 4; ++mt)
      fa[mt] = *(const bf16x8*)&As[(wm + mt * 16 + lm) * GLDA + kq * 8];
    #pragma unroll
    for (int nt = 0; nt < 4; ++nt)
      fb[nt] = *(const bf16x8*)&Bs[(wn + nt * 16 + lm) * GLDA + kq * 8];
    #pragma unroll
    for (int mt = 0; mt < 4; ++mt)
      #pragma unroll
      for (int nt = 0; nt < 4; ++nt)
        acc[mt][nt] = __builtin_amdgcn_mfma_f32_16x16x32_bf16(fa[mt], fb[nt], acc[mt][nt], 0, 0, 0);
  }
  #pragma unroll
  for (int mt = 0; mt < 4; ++mt)
    #pragma unroll
    for (int nt = 0; nt < 4; ++nt) {
      int col = bn + wn + nt * 16 + lm;
      if (col >= N) continue;
      float bz = bias[col];
      #pragma unroll
      for (int i = 0; i < 4; ++i) {
        int row = bm + wm + mt * 16 + kq * 4 + i;
        float v = acc[mt][nt][i] + bz;
        if (mode == 0) {
          Cf[(size_t)row * N + col] = v;
        } else if (mode == 1) {
          Cb[(size_t)row * N + col] = (__bf16)v;
        } else {
          if (col < 512) Cb[(size_t)row * 512 + col] = (__bf16)v;
          else           Cg[(size_t)row * 512 + col - 512] = (__bf16)silu(v);
        }
      }
    }
}

// ---------------- depthwise causal conv (k=4) + SiLU, bf16 in/out, 4 ch/thread
__global__ void conv_silu(const __bf16* __restrict__ xs,
                          const float* __restrict__ cw,
                          const float* __restrict__ cb,
                          __bf16* __restrict__ xc, int total) {
  int idx = blockIdx.x * 256 + threadIdx.x;   // < R*128
  if (idx >= total) return;
  int d4 = (idx & 127) * 4;
  int bt = idx >> 7;
  int t = bt % SEQC;
  const __bf16* base = xs + (size_t)(bt - t) * 512 + d4;
  float4 w0 = *(const float4*)&cw[(d4 + 0) * 4];
  float4 w1 = *(const float4*)&cw[(d4 + 1) * 4];
  float4 w2 = *(const float4*)&cw[(d4 + 2) * 4];
  float4 w3 = *(const float4*)&cw[(d4 + 3) * 4];
  float4 b4 = *(const float4*)&cb[d4];
  float acc[4] = {b4.x, b4.y, b4.z, b4.w};
  float wv[4][4] = {{w0.x, w0.y, w0.z, w0.w}, {w1.x, w1.y, w1.z, w1.w},
                    {w2.x, w2.y, w2.z, w2.w}, {w3.x, w3.y, w3.z, w3.w}};
  #pragma unroll
  for (int j = 0; j < 4; ++j) {
    int ts = t - 3 + j;
    if (ts >= 0) {
      bf16x4 v = *(const bf16x4*)&base[(size_t)ts * 512];
      #pragma unroll
      for (int e = 0; e < 4; ++e) acc[e] = fmaf(wv[e][j], (float)v[e], acc[e]);
    }
  }
  bf16x4 o;
  #pragma unroll
  for (int e = 0; e < 4; ++e) o[e] = (__bf16)silu(acc[e]);
  *(bf16x4*)&xc[(size_t)bt * 512 + d4] = o;
}

// ---------------- scan phase 1: per-chunk local scan (h=0) -> hend, P (bf16)
__global__ __launch_bounds__(64) void scan_phase1(
    const __bf16* __restrict__ ssm, const float* __restrict__ A_log,
    const __bf16* __restrict__ xc,
    __bf16* __restrict__ hend, __bf16* __restrict__ Pp) {
  __shared__ float sb[SUB * 32];
  __shared__ __bf16 xsb[SUB * 64];
  int b = blockIdx.x, dgi = blockIdx.y, c = blockIdx.z;
  int dg = dgi * 64, lane = threadIdx.x, d = dg + lane;
  float a[16];
  #pragma unroll
  for (int n = 0; n < 16; ++n) a[n] = -__expf(A_log[d * 16 + n]);
  float h[16] = {}, S[16] = {};
  size_t rowbase = (size_t)b * SEQC + c * CT;

  for (int sub = 0; sub < 2; ++sub) {
    int ts0 = sub * SUB;
    __syncthreads();
    for (int i = lane; i < SUB * 8; i += 64) {
      int tt = i >> 3, n4 = (i & 7) * 4;
      bf16x4 v = *(const bf16x4*)&ssm[(rowbase + ts0 + tt) * 32 + n4];
      float4 f = {(float)v[0], (float)v[1], (float)v[2], (float)v[3]};
      if (n4 < 16) { f.x = sp(f.x); f.y = sp(f.y); f.z = sp(f.z); f.w = sp(f.w); }
      *(float4*)&sb[tt * 32 + n4] = f;
    }
    for (int i = lane; i < SUB * 16; i += 64) {
      int tt = i >> 4, j4 = (i & 15) * 4;
      *(bf16x4*)&xsb[tt * 64 + j4] =
          *(const bf16x4*)&xc[(rowbase + ts0 + tt) * 512 + dg + j4];
    }
    __syncthreads();
    for (int tt = 0; tt < SUB; ++tt) {
      const float4* dv = (const float4*)&sb[tt * 32];
      float4 d0 = dv[0], d1 = dv[1], d2 = dv[2], d3 = dv[3];
      float4 e0 = dv[4], e1 = dv[5], e2 = dv[6], e3 = dv[7];
      float del[16] = {d0.x, d0.y, d0.z, d0.w, d1.x, d1.y, d1.z, d1.w,
                       d2.x, d2.y, d2.z, d2.w, d3.x, d3.y, d3.z, d3.w};
      float Bv[16]  = {e0.x, e0.y, e0.z, e0.w, e1.x, e1.y, e1.z, e1.w,
                       e2.x, e2.y, e2.z, e2.w, e3.x, e3.y, e3.z, e3.w};
      float xv = (float)xsb[tt * 64 + lane];
      #pragma unroll
      for (int n = 0; n < 16; ++n) {
        S[n] += del[n];
        float e = __expf(a[n] * del[n]);
        h[n] = fmaf(h[n], e, xv * Bv[n]);
      }
    }
  }
  size_t base = ((size_t)(b * NCH + c) * 512 + d) * 16;
  bf16x8 h0, h1, p0, p1;
  #pragma unroll
  for (int n = 0; n < 8; ++n) {
    h0[n] = (__bf16)h[n]; h1[n] = (__bf16)h[n + 8];
    p0[n] = (__bf16)__expf(a[n] * S[n]);
    p1[n] = (__bf16)__expf(a[n + 8] * S[n + 8]);
  }
  *(bf16x8*)&hend[base] = h0; *(bf16x8*)&hend[base + 8] = h1;
  *(bf16x8*)&Pp[base] = p0;   *(bf16x8*)&Pp[base + 8] = p1;
}

// ---------------- scan phase 2: sequential carry composition (hend -> hin in place)
__global__ __launch_bounds__(64) void scan_combine(
    __bf16* __restrict__ hend, const __bf16* __restrict__ Pp) {
  int b = blockIdx.x;
  int d = blockIdx.y * 64 + threadIdx.x;
  float hp[16] = {};
  for (int c = 0; c < NCH; ++c) {
    size_t base = ((size_t)(b * NCH + c) * 512 + d) * 16;
    bf16x8 he0 = *(const bf16x8*)&hend[base];
    bf16x8 he1 = *(const bf16x8*)&hend[base + 8];
    bf16x8 pp0 = *(const bf16x8*)&Pp[base];
    bf16x8 pp1 = *(const bf16x8*)&Pp[base + 8];
    bf16x8 o0, o1;
    #pragma unroll
    for (int n = 0; n < 8; ++n) {
      o0[n] = (__bf16)hp[n]; o1[n] = (__bf16)hp[n + 8];
      hp[n]     = fmaf((float)pp0[n], hp[n],     (float)he0[n]);
      hp[n + 8] = fmaf((float)pp1[n], hp[n + 8], (float)he1[n]);
    }
    *(bf16x8*)&hend[base] = o0; *(bf16x8*)&hend[base + 8] = o1;
  }
}

// ---------------- scan phase 3: local scan with carry, y, gate -> yc bf16
__global__ __launch_bounds__(64) void scan_phase3(
    const __bf16* __restrict__ ssm, const float* __restrict__ A_log,
    const float* __restrict__ Dp, const __bf16* __restrict__ xc,
    const __bf16* __restrict__ gate, const __bf16* __restrict__ hin,
    __bf16* __restrict__ yc) {
  __shared__ float sb[SUB * 32];
  __shared__ __bf16 xsb[SUB * 64];
  int b = blockIdx.x, dgi = blockIdx.y, c = blockIdx.z;
  int dg = dgi * 64, lane = threadIdx.x, d = dg + lane;
  float a[16];
  #pragma unroll
  for (int n = 0; n < 16; ++n) a[n] = -__expf(A_log[d * 16 + n]);
  float Dv = Dp[d];
  float h[16];
  {
    size_t base = ((size_t)(b * NCH + c) * 512 + d) * 16;
    bf16x8 h0 = *(const bf16x8*)&hin[base];
    bf16x8 h1 = *(const bf16x8*)&hin[base + 8];
    #pragma unroll
    for (int n = 0; n < 8; ++n) { h[n] = (float)h0[n]; h[n + 8] = (float)h1[n]; }
  }
  size_t rowbase = (size_t)b * SEQC + c * CT;

  for (int sub = 0; sub < 2; ++sub) {
    int ts0 = sub * SUB;
    __syncthreads();
    for (int i = lane; i < SUB * 8; i += 64) {
      int tt = i >> 3, n4 = (i & 7) * 4;
      bf16x4 v = *(const bf16x4*)&ssm[(rowbase + ts0 + tt) * 32 + n4];
      float4 f = {(float)v[0], (float)v[1], (float)v[2], (float)v[3]};
      if (n4 < 16) { f.x = sp(f.x); f.y = sp(f.y); f.z = sp(f.z); f.w = sp(f.w); }
      *(float4*)&sb[tt * 32 + n4] = f;
    }
    for (int i = lane; i < SUB * 16; i += 64) {
      int tt = i >> 4, j4 = (i & 15) * 4;
      *(bf16x4*)&xsb[tt * 64 + j4] =
          *(const bf16x4*)&xc[(rowbase + ts0 + tt) * 512 + dg + j4];
    }
    __syncthreads();
    for (int tt = 0; tt < SUB; ++tt) {
      const float4* dv = (const float4*)&sb[tt * 32];
      float4 d0 = dv[0], d1 = dv[1], d2 = dv[2], d3 = dv[3];
      float4 e0 = dv[4], e1 = dv[5], e2 = dv[6], e3 = dv[7];
      float del[16] = {d0.x, d0.y, d0.z, d0.w, d1.x, d1.y, d1.z, d1.w,
                       d2.x, d2.y, d2.z, d2.w, d3.x, d3.y, d3.z, d3.w};
      float Bv[16]  = {e0.x, e0.y, e0.z, e0.w, e1.x, e1.y, e1.z, e1.w,
                       e2.x, e2.y, e2.z, e2.w, e3.x, e3.y, e3.z, e3.w};
      float xv = (float)xsb[tt * 64 + lane];
      float y0 = 0.f, y1 = 0.f, y2 = 0.f, y3 = 0.f;
      #pragma unroll
      for (int n = 0; n < 4; ++n) {
        float e = __expf(a[n] * del[n]);
        h[n] = fmaf(h[n], e, xv * Bv[n]);
        y0 = fmaf(h[n], Bv[n], y0);
      }
      #pragma unroll
      for (int n = 4; n < 8; ++n) {
        float e = __expf(a[n] * del[n]);
        h[n] = fmaf(h[n], e, xv * Bv[n]);
        y1 = fmaf(h[n], Bv[n], y1);
      }
      #pragma unroll
      for (int n = 8; n < 12; ++n) {
        float e = __expf(a[n] * del[n]);
        h[n] = fmaf(h[n], e, xv * Bv[n]);
        y2 = fmaf(h[n], Bv[n], y2);
      }
      #pragma unroll
      for (int n = 12; n < 16; ++n) {
        float e = __expf(a[n] * del[n]);
        h[n] = fmaf(h[n], e, xv * Bv[n]);
        y3 = fmaf(h[n], Bv[n], y3);
      }
      xsb[tt * 64 + lane] = (__bf16)fmaf(Dv, xv, (y0 + y1) + (y2 + y3));
    }
    __syncthreads();
    for (int i = lane; i < SUB * 16; i += 64) {
      int tt = i >> 4, j4 = (i & 15) * 4;
      size_t o = (rowbase + ts0 + tt) * 512 + dg + j4;
      bf16x4 y4 = *(const bf16x4*)&xsb[tt * 64 + j4];
      bf16x4 g4 = *(const bf16x4*)&gate[o];
      bf16x4 r;
      #pragma unroll
      for (int e = 0; e < 4; ++e) r[e] = (__bf16)((float)y4[e] * (float)g4[e]);
      *(bf16x4*)&yc[o] = r;
    }
  }
}

// ---------------- x = LayerNorm(reconstruct(xh,xl) + ob), re-split
__global__ __launch_bounds__(64) void add_ln(
    __bf16* __restrict__ xh, __bf16* __restrict__ xl,
    const float* __restrict__ ob,
    const float* __restrict__ g, const float* __restrict__ bb) {
  size_t base = (size_t)blockIdx.x * 256;
  int lane = threadIdx.x;
  bf16x4 h4 = *(const bf16x4*)&xh[base + lane * 4];
  bf16x4 l4 = *(const bf16x4*)&xl[base + lane * 4];
  float4 o4 = *(const float4*)&ob[base + lane * 4];
  float ov[4] = {o4.x, o4.y, o4.z, o4.w};
  float v[4];
  #pragma unroll
  for (int i = 0; i < 4; ++i) v[i] = (float)h4[i] + (float)l4[i] + ov[i];
  float s = v[0] + v[1] + v[2] + v[3];
  #pragma unroll
  for (int off = 32; off > 0; off >>= 1) s += __shfl_down(s, off);
  float mu = __shfl(s, 0) * (1.f / 256.f);
  float var = 0.f;
  #pragma unroll
  for (int i = 0; i < 4; ++i) { float dd = v[i] - mu; var = fmaf(dd, dd, var); }
  #pragma unroll
  for (int off = 32; off > 0; off >>= 1) var += __shfl_down(var, off);
  float r = rsqrtf(__shfl(var, 0) * (1.f / 256.f) + LN_EPSF);
  float4 gv = *(const float4*)&g[lane * 4];
  float4 bv = *(const float4*)&bb[lane * 4];
  float gg[4] = {gv.x, gv.y, gv.z, gv.w};
  float bbv[4] = {bv.x, bv.y, bv.z, bv.w};
  bf16x4 hq, lq;
  #pragma unroll
  for (int i = 0; i < 4; ++i) {
    float o = (v[i] - mu) * r * gg[i] + bbv[i];
    __bf16 hh = (__bf16)o;
    hq[i] = hh;
    lq[i] = (__bf16)(o - (float)hh);
  }
  *(bf16x4*)&xh[base + lane * 4] = hq;
  *(bf16x4*)&xl[base + lane * 4] = lq;
}

// ---------------- fin[b][256] = reconstruct(x) at t=899
__global__ void extract_final(const __bf16* __restrict__ xh,
                              const __bf16* __restrict__ xl,
                              float* __restrict__ fin) {
  int b = blockIdx.x;
  int c = threadIdx.x;
  size_t o = ((size_t)b * SEQC + (SEQC - 1)) * D_MODELC + c;
  fin[(size_t)b * 256 + c] = (float)xh[o] + (float)xl[o];
}

// ---------------- final heads
__global__ __launch_bounds__(128) void heads_kernel(
    const float* __restrict__ fin,
    const float* __restrict__ cnt1_w, const float* __restrict__ cnt1_b,
    const float* __restrict__ cnt2_w, const float* __restrict__ cnt2_b,
    const float* __restrict__ col1_w, const float* __restrict__ col1_b,
    const float* __restrict__ col2_w, const float* __restrict__ col2_b,
    float* __restrict__ out) {
  int b = blockIdx.x;
  int tid = threadIdx.x;
  __shared__ float f[256];
  __shared__ float hc[128];
  __shared__ float hl[128];
  f[tid] = fin[b * 256 + tid];
  f[tid + 128] = fin[b * 256 + tid + 128];
  __syncthreads();
  float s1 = cnt1_b[tid], s2 = col1_b[tid];
  for (int c = 0; c < 256; ++c) {
    float v = f[c];
    s1 = fmaf(v, cnt1_w[c * 128 + tid], s1);
    s2 = fmaf(v, col1_w[c * 128 + tid], s2);
  }
  hc[tid] = fmaxf(s1, 0.f);
  hl[tid] = fmaxf(s2, 0.f);
  __syncthreads();
  if (tid == 0) {
    float t = cnt2_b[0];
    for (int j = 0; j < 128; ++j) t = fmaf(hc[j], cnt2_w[j], t);
    out[b] = fmaxf(t, 0.f);
  }
  if (tid < 10) {
    float t = col2_b[tid];
    for (int j = 0; j < 128; ++j) t = fmaf(hl[j], col2_w[j * 10 + tid], t);
    out[64 + b * 10 + tid] = fmaxf(t, 0.f);
  }
}

extern "C" void kernel_launch(void* const* d_in, const int* in_sizes, int n_in,
                              void* d_out, int out_size, void* d_ws, size_t ws_size,
                              hipStream_t stream) {
  const int*   grid   = (const int*)d_in[0];
  const float* cemb   = (const float*)d_in[1];
  const float* pemb   = (const float*)d_in[2];
  const float* in_w   = (const float*)d_in[3];
  const float* in_b   = (const float*)d_in[4];
  const float* conv_w = (const float*)d_in[5];
  const float* conv_b = (const float*)d_in[6];
  const float* xproj_w= (const float*)d_in[7];
  const float* xproj_b= (const float*)d_in[8];
  const float* A_log  = (const float*)d_in[9];
  const float* Dp     = (const float*)d_in[10];
  const float* out_w  = (const float*)d_in[11];
  const float* out_b  = (const float*)d_in[12];
  const float* ln_g   = (const float*)d_in[13];
  const float* ln_b   = (const float*)d_in[14];
  const float* cnt1_w = (const float*)d_in[15];
  const float* cnt1_b = (const float*)d_in[16];
  const float* cnt2_w = (const float*)d_in[17];
  const float* cnt2_b = (const float*)d_in[18];
  const float* col1_w = (const float*)d_in[19];
  const float* col1_b = (const float*)d_in[20];
  const float* col2_w = (const float*)d_in[21];
  const float* col2_b = (const float*)d_in[22];

  const int R = BATCHC * SEQC;  // 57600
  float* ws = (float*)d_ws;
  size_t off = 0;
  auto alloc = [&](size_t fl) { float* p = ws + off; off += (fl + 63) & ~(size_t)63; return p; };

  float*  fin   = alloc((size_t)BATCHC * 256);
  __bf16* wi    = (__bf16*)alloc((size_t)N_LAYERSC * 1024 * 256 / 2);
  __bf16* wx    = (__bf16*)alloc((size_t)N_LAYERSC * 32 * 512 / 2);
  __bf16* wo    = (__bf16*)alloc((size_t)N_LAYERSC * 256 * 512 / 2);
  __bf16* xh    = (__bf16*)alloc((size_t)R * 256 / 2);
  __bf16* xl    = (__bf16*)alloc((size_t)R * 256 / 2);
  __bf16* xsyc  = (__bf16*)alloc((size_t)R * 512 / 2);   // xs then yc
  float*  gateob= alloc((size_t)R * 512 / 2);            // gate bf16, then ob fp32
  __bf16* xc    = (__bf16*)alloc((size_t)R * 512 / 2);
  __bf16* ssm   = (__bf16*)alloc((size_t)R * 32 / 2);
  __bf16* hend  = (__bf16*)alloc((size_t)BATCHC * NCH * 512 * 16 / 2);
  __bf16* Pp    = (__bf16*)alloc((size_t)BATCHC * NCH * 512 * 16 / 2);
  __bf16* gate  = (__bf16*)gateob;
  float*  ob    = gateob;

  // weight prep (once per call)
  wprep<<<dim3(1024, N_LAYERSC), 256, 0, stream>>>(in_w, wi, 256, 1024, 8);
  wprep<<<dim3(64, N_LAYERSC), 256, 0, stream>>>(xproj_w, wx, 512, 32, 9);
  wprep<<<dim3(512, N_LAYERSC), 256, 0, stream>>>(out_w, wo, 512, 256, 9);

  embed_kernel<<<R, 256, 0, stream>>>(grid, cemb, pemb, xh, xl);

  for (int l = 0; l < N_LAYERSC; ++l) {
    // in-proj: xs (bf16) + gate = silu(res) (bf16)
    gemm_bf16<<<dim3(R / 128, 8), 256, 0, stream>>>(
        xh, wi + (size_t)l * 1024 * 256, in_b + l * 1024,
        nullptr, xsyc, gate, R, 1024, 256, 2);
    conv_silu<<<(R * 128 + 255) / 256, 256, 0, stream>>>(
        xsyc, conv_w + (size_t)l * 512 * 4, conv_b + l * 512, xc, R * 128);
    // x-proj: ssm bf16
    gemm_bf16<<<dim3(R / 128, 1), 256, 0, stream>>>(
        xc, wx + (size_t)l * 32 * 512, xproj_b + l * 32,
        nullptr, ssm, nullptr, R, 32, 512, 1);
    scan_phase1<<<dim3(BATCHC, 8, NCH), 64, 0, stream>>>(
        ssm, A_log + (size_t)l * 512 * 16, xc, hend, Pp);
    scan_combine<<<dim3(BATCHC, 8), 64, 0, stream>>>(hend, Pp);
    scan_phase3<<<dim3(BATCHC, 8, NCH), 64, 0, stream>>>(
        ssm, A_log + (size_t)l * 512 * 16, Dp + l * 512, xc, gate, hend, xsyc);
    // out-proj: ob fp32
    gemm_bf16<<<dim3(R / 128, 2), 256, 0, stream>>>(
        xsyc, wo + (size_t)l * 256 * 512, out_b + l * 256,
        ob, nullptr, nullptr, R, 256, 512, 0);
    add_ln<<<R, 64, 0, stream>>>(xh, xl, ob, ln_g, ln_b);
  }

  extract_final<<<BATCHC, 256, 0, stream>>>(xh, xl, fin);
  heads_kernel<<<BATCHC, 128, 0, stream>>>(
      fin, cnt1_w, cnt1_b, cnt2_w, cnt2_b, col1_w, col1_b, col2_w, col2_b,
      (float*)d_out);
}